// Round 18
// baseline (360.532 us; speedup 1.0000x reference)
//
#include <hip/hip_runtime.h>
#include <hip/hip_bf16.h>
#include <stdint.h>

#define D_ 1024
#define H_ 16
#define DH_ 64
#define S_ 2048
#define B_ 16
static constexpr float SCALE = 0.125f;  // 1/sqrt(64)

typedef __bf16 bf16_t;
typedef __bf16 bf16x8 __attribute__((ext_vector_type(8)));
typedef __bf16 bf16x4 __attribute__((ext_vector_type(4)));
typedef float  f32x4  __attribute__((ext_vector_type(4)));

__device__ __forceinline__ void llds16(const void* g, void* l) {
  __builtin_amdgcn_global_load_lds(
      (const __attribute__((address_space(1))) void*)g,
      (__attribute__((address_space(3))) void*)l, 16, 0, 0);
}

// ---------------------------------------------------------------------------
// prep_all: one launch for all input preprocessing.
// ---------------------------------------------------------------------------
__global__ __launch_bounds__(256)
void prep_all(const float* __restrict__ Wq, const float* __restrict__ Wk,
              const float* __restrict__ Wt, const float* __restrict__ Wqa,
              const float* __restrict__ Wka, const float* __restrict__ hs,
              bf16_t* __restrict__ WqT, bf16_t* __restrict__ WkT,
              bf16_t* __restrict__ WtT, bf16_t* __restrict__ WqaT,
              bf16_t* __restrict__ WkaT, bf16_t* __restrict__ hsb) {
  __shared__ bf16_t t[64][65];
  const int z = blockIdx.z;
  const int tid = threadIdx.x;
  if (z < 3) {
    const float* src = (z == 0) ? Wq : (z == 1) ? Wk : Wt;
    bf16_t* dst      = (z == 0) ? WqT : (z == 1) ? WkT : WtT;
    const int n0 = blockIdx.x * 64, k0 = blockIdx.y * 64;
    const int r = tid >> 4, c4 = (tid & 15) * 4;
#pragma unroll
    for (int p = 0; p < 4; ++p) {
      int row = p * 16 + r;
      f32x4 f = *(const f32x4*)&src[(size_t)(k0 + row) * 1024 + n0 + c4];
#pragma unroll
      for (int i = 0; i < 4; ++i) t[row][c4 + i] = (bf16_t)f[i];
    }
    __syncthreads();
#pragma unroll
    for (int p = 0; p < 4; ++p) {
      int row = p * 16 + r;
      bf16x4 v;
#pragma unroll
      for (int i = 0; i < 4; ++i) v[i] = t[c4 + i][row];
      *(bf16x4*)&dst[(size_t)(n0 + row) * 1024 + k0 + c4] = v;
    }
  } else if (z == 3) {
    int g = (blockIdx.y * 16 + blockIdx.x) * 256 + tid;
    if (g < 2048) {
      const float* src = (g < 1024) ? Wqa : Wka;
      bf16_t* dst      = (g < 1024) ? WqaT : WkaT;
      int k = g & 1023;
#pragma unroll
      for (int h = 0; h < H_; ++h) dst[h * 1024 + k] = (bf16_t)src[k * H_ + h];
    }
  } else {
    const int slice = z - 4;
    const int fb = blockIdx.y * 16 + blockIdx.x;
    const size_t tbase = ((size_t)slice * 256 + fb) * 256 + tid;
#pragma unroll
    for (int i = 0; i < 4; ++i) {
      size_t e = (tbase + (size_t)i * 1048576) * 8;
      f32x4 a = *(const f32x4*)&hs[e];
      f32x4 b = *(const f32x4*)&hs[e + 4];
      bf16x8 o;
#pragma unroll
      for (int j = 0; j < 4; ++j) { o[j] = (bf16_t)a[j]; o[4 + j] = (bf16_t)b[j]; }
      *(bf16x8*)&hsb[e] = o;
    }
  }
}

// ---------------------------------------------------------------------------
// Dual-N 256x256 8-phase GEMM with PER-PHASE BARRIERS (m201-faithful):
// each phase = {stage half-tile; [vmcnt(6)+barrier at ph1/ph3]; ds_read
// quadrant; lgkmcnt(0)+sched_barrier; setprio 16-MFMA; barrier}. The barrier
// lock creates the wave role-split that makes setprio pay (m218b); landing
// guarantees identical to r16 (same vmcnt counting, refcheck'd).
// ---------------------------------------------------------------------------
__global__ __launch_bounds__(512, 1)
void gemm_qk(const bf16_t* __restrict__ A, const bf16_t* __restrict__ WqT,
             const bf16_t* __restrict__ WkT, const float* __restrict__ bq,
             const float* __restrict__ bk, bf16_t* __restrict__ mq,
             bf16_t* __restrict__ mk) {
  constexpr int K = 1024, N = 1024;
  __shared__ __align__(16) bf16_t lds[2][2][2][256 * 32];
  const int tid = threadIdx.x;
  const int lane = tid & 63, wid = tid >> 6;
  const int wm = wid >> 2, wn = wid & 3;

  const int wgid = (blockIdx.x & 7) * 128 + (blockIdx.x >> 3);
  const int m0 = (wgid >> 3) * 256;
  const int nsel = wgid & 7;
  const int n0 = (nsel & 3) * 256;
  const bf16_t* BT = (nsel < 4) ? WqT : WkT;
  const float* bias = (nsel < 4) ? bq : bk;
  bf16_t* Cout = (nsel < 4) ? mq : mk;

  int srow[2], scol[2];
#pragma unroll
  for (int ld = 0; ld < 2; ++ld) {
    int c = ld * 512 + tid;
    srow[ld] = c >> 2;
    scol[ld] = (((c & 3) - ((srow[ld] >> 1) & 3)) & 3) * 8;
  }

  const int ar = lane & 15;
  const int kc = lane >> 4;

  f32x4 acc[8][4] = {};

#define STAGE_(MAT, KH, KOFF, NXT)                                             \
  {                                                                            \
    const bf16_t* srcb = (MAT == 0) ? A : BT;                                  \
    const int rb = (MAT == 0) ? m0 : n0;                                       \
    _Pragma("unroll")                                                          \
    for (int ld = 0; ld < 2; ++ld) {                                           \
      llds16(srcb + (size_t)(rb + srow[ld]) * K + (KOFF) + (KH) * 32 + scol[ld], \
             &lds[NXT][MAT][KH][(ld * 512 + tid) * 8]);                        \
    }                                                                          \
  }

// ds_read quadrant -> full-drain lgkmcnt -> pinned MFMA cluster (rule #18)
#define COMPUTE_(KH, MH, CUR)                                                  \
  {                                                                            \
    bf16x8 af[4], bg[4];                                                       \
    _Pragma("unroll")                                                          \
    for (int mm = 0; mm < 4; ++mm) {                                           \
      int r = wm * 128 + ((MH) * 4 + mm) * 16 + ar;                            \
      int slot = (kc + ((r >> 1) & 3)) & 3;                                    \
      af[mm] = *(const bf16x8*)&lds[CUR][0][KH][r * 32 + slot * 8];            \
    }                                                                          \
    _Pragma("unroll")                                                          \
    for (int nn = 0; nn < 4; ++nn) {                                           \
      int r = wn * 64 + nn * 16 + ar;                                          \
      int slot = (kc + ((r >> 1) & 3)) & 3;                                    \
      bg[nn] = *(const bf16x8*)&lds[CUR][1][KH][r * 32 + slot * 8];            \
    }                                                                          \
    asm volatile("s_waitcnt lgkmcnt(0)" ::: "memory");                         \
    __builtin_amdgcn_sched_barrier(0);                                         \
    __builtin_amdgcn_s_setprio(1);                                             \
    _Pragma("unroll")                                                          \
    for (int mm = 0; mm < 4; ++mm)                                             \
      _Pragma("unroll")                                                        \
      for (int nn = 0; nn < 4; ++nn)                                           \
        acc[(MH) * 4 + mm][nn] = __builtin_amdgcn_mfma_f32_16x16x32_bf16(      \
            af[mm], bg[nn], acc[(MH) * 4 + mm][nn], 0, 0, 0);                  \
    __builtin_amdgcn_s_setprio(0);                                             \
  }

  STAGE_(0, 0, 0, 0); STAGE_(1, 0, 0, 0); STAGE_(0, 1, 0, 0); STAGE_(1, 1, 0, 0);

#pragma unroll 1
  for (int t = 0; t < 15; ++t) {
    const int cur = t & 1, nxt = cur ^ 1;
    const int koff = (t + 1) * 64;
    // ph1: landing guarantee for tile t kh0 (vmcnt leaves t-kh1 + t+1-A-kh0)
    STAGE_(0, 0, koff, nxt);
    asm volatile("s_waitcnt vmcnt(6)" ::: "memory");
    __builtin_amdgcn_s_barrier();
    COMPUTE_(0, 0, cur);
    __builtin_amdgcn_s_barrier();
    // ph2 (kh0 already landed)
    STAGE_(1, 0, koff, nxt);
    COMPUTE_(0, 1, cur);
    __builtin_amdgcn_s_barrier();
    // ph3: landing guarantee for tile t kh1
    STAGE_(0, 1, koff, nxt);
    asm volatile("s_waitcnt vmcnt(6)" ::: "memory");
    __builtin_amdgcn_s_barrier();
    COMPUTE_(1, 0, cur);
    __builtin_amdgcn_s_barrier();
    // ph4
    STAGE_(1, 1, koff, nxt);
    COMPUTE_(1, 1, cur);
    __builtin_amdgcn_s_barrier();
  }
  // peeled last tile (t=15, cur=1): no staging
  asm volatile("s_waitcnt vmcnt(4)" ::: "memory");
  __builtin_amdgcn_s_barrier();
  COMPUTE_(0, 0, 1);
  COMPUTE_(0, 1, 1);
  asm volatile("s_waitcnt vmcnt(0)" ::: "memory");
  __builtin_amdgcn_s_barrier();
  COMPUTE_(1, 0, 1);
  COMPUTE_(1, 1, 1);
#undef STAGE_
#undef COMPUTE_

  __syncthreads();

  float* st = (float*)&lds[0][0][0][0] + wid * (16 * 68);
  const int erow = lane >> 2;
  const int ecol = (lane & 3) * 16;
  const int gcb = n0 + wn * 64;
  const int qrow = (lane >> 4) * 4;
  const int qcol = lane & 15;
  f32x4 bb[4];
#pragma unroll
  for (int q = 0; q < 4; ++q) bb[q] = *(const f32x4*)&bias[gcb + ecol + q * 4];
#pragma unroll
  for (int m = 0; m < 8; ++m) {
#pragma unroll
    for (int n = 0; n < 4; ++n)
#pragma unroll
      for (int j = 0; j < 4; ++j)
        st[(qrow + j) * 68 + n * 16 + qcol] = acc[m][n][j];
    asm volatile("s_waitcnt lgkmcnt(0)" ::: "memory");
    __builtin_amdgcn_sched_barrier(0);
    const int grow = m0 + wm * 128 + m * 16 + erow;
    f32x4 v[4];
#pragma unroll
    for (int q = 0; q < 4; ++q) v[q] = *(f32x4*)&st[erow * 68 + ecol + q * 4];
#pragma unroll
    for (int q = 0; q < 4; ++q)
#pragma unroll
      for (int i = 0; i < 4; ++i) v[q][i] += bb[q][i];
    bf16x8 o0, o1;
#pragma unroll
    for (int i = 0; i < 4; ++i) { o0[i] = (bf16_t)v[0][i]; o0[4 + i] = (bf16_t)v[1][i]; }
#pragma unroll
    for (int i = 0; i < 4; ++i) { o1[i] = (bf16_t)v[2][i]; o1[4 + i] = (bf16_t)v[3][i]; }
    bf16_t* op = Cout + (size_t)grow * N + gcb + ecol;
    *(bf16x8*)&op[0] = o0;
    *(bf16x8*)&op[8] = o1;
  }
}

// ---------------------------------------------------------------------------
// wt_s[b][n][k] = bf16(pk[b,k] * WtT[n,k])
// ---------------------------------------------------------------------------
__global__ __launch_bounds__(256)
void wt_scale(const bf16_t* __restrict__ WtT, const float* __restrict__ pk,
              bf16_t* __restrict__ wt_s) {
  size_t e = ((size_t)blockIdx.x * 256 + threadIdx.x) * 8;
  const int b = (int)(e >> 20);
  const int nk = (int)(e & 1048575);
  const int k = nk & 1023;
  bf16x8 w = *(const bf16x8*)&WtT[nk];
  const float* pp = &pk[b * D_ + k];
  f32x4 p0 = *(const f32x4*)pp;
  f32x4 p1 = *(const f32x4*)(pp + 4);
  bf16x8 o;
#pragma unroll
  for (int i = 0; i < 4; ++i) {
    o[i]     = (bf16_t)((float)w[i] * p0[i]);
    o[4 + i] = (bf16_t)((float)w[4 + i] * p1[i]);
  }
  *(bf16x8*)&wt_s[e] = o;
}

// ---------------------------------------------------------------------------
// Final GEMM, 8-phase (r16 form, unchanged): out = mq @ wt_s[b] + bt + resid
// ---------------------------------------------------------------------------
__global__ __launch_bounds__(512, 1)
void gemm_out8(const bf16_t* __restrict__ A, const bf16_t* __restrict__ WtS,
               const float* __restrict__ bias, float* __restrict__ Cout,
               const bf16_t* __restrict__ resid) {
  constexpr int K = 1024, N = 1024;
  __shared__ __align__(16) bf16_t lds[2][2][2][256 * 32];
  const int tid = threadIdx.x;
  const int lane = tid & 63, wid = tid >> 6;
  const int wm = wid >> 2, wn = wid & 3;

  const int wgid = (blockIdx.x & 7) * 64 + (blockIdx.x >> 3);
  const int m0 = (wgid >> 2) * 256;
  const int n0 = (wgid & 3) * 256;
  const bf16_t* BT = WtS + ((size_t)(m0 >> 11) << 20);

  int srow[2], scol[2];
#pragma unroll
  for (int ld = 0; ld < 2; ++ld) {
    int c = ld * 512 + tid;
    srow[ld] = c >> 2;
    scol[ld] = (((c & 3) - ((srow[ld] >> 1) & 3)) & 3) * 8;
  }

  const int ar = lane & 15;
  const int kc = lane >> 4;

  f32x4 acc[8][4] = {};

#define STAGE2_(MAT, KH, KOFF, NXT)                                            \
  {                                                                            \
    const bf16_t* srcb = (MAT == 0) ? A : BT;                                  \
    const int rb = (MAT == 0) ? m0 : n0;                                       \
    _Pragma("unroll")                                                          \
    for (int ld = 0; ld < 2; ++ld) {                                           \
      llds16(srcb + (size_t)(rb + srow[ld]) * K + (KOFF) + (KH) * 32 + scol[ld], \
             &lds[NXT][MAT][KH][(ld * 512 + tid) * 8]);                        \
    }                                                                          \
  }

#define COMPUTE2_(KH, MH, CUR)                                                 \
  {                                                                            \
    bf16x8 af[4], bg[4];                                                       \
    _Pragma("unroll")                                                          \
    for (int mm = 0; mm < 4; ++mm) {                                           \
      int r = wm * 128 + ((MH) * 4 + mm) * 16 + ar;                            \
      int slot = (kc + ((r >> 1) & 3)) & 3;                                    \
      af[mm] = *(const bf16x8*)&lds[CUR][0][KH][r * 32 + slot * 8];            \
    }                                                                          \
    _Pragma("unroll")                                                          \
    for (int nn = 0; nn < 4; ++nn) {                                           \
      int r = wn * 64 + nn * 16 + ar;                                          \
      int slot = (kc + ((r >> 1) & 3)) & 3;                                    \
      bg[nn] = *(const bf16x8*)&lds[CUR][1][KH][r * 32 + slot * 8];            \
    }                                                                          \
    __builtin_amdgcn_s_setprio(1);                                             \
    _Pragma("unroll")                                                          \
    for (int mm = 0; mm < 4; ++mm)                                             \
      _Pragma("unroll")                                                        \
      for (int nn = 0; nn < 4; ++nn)                                           \
        acc[(MH) * 4 + mm][nn] = __builtin_amdgcn_mfma_f32_16x16x32_bf16(      \
            af[mm], bg[nn], acc[(MH) * 4 + mm][nn], 0, 0, 0);                  \
    __builtin_amdgcn_s_setprio(0);                                             \
  }

  STAGE2_(0, 0, 0, 0); STAGE2_(1, 0, 0, 0); STAGE2_(0, 1, 0, 0); STAGE2_(1, 1, 0, 0);

#pragma unroll 1
  for (int t = 0; t < 15; ++t) {
    const int cur = t & 1, nxt = cur ^ 1;
    const int koff = (t + 1) * 64;
    STAGE2_(0, 0, koff, nxt);
    asm volatile("s_waitcnt vmcnt(6)" ::: "memory");
    __builtin_amdgcn_s_barrier();
    COMPUTE2_(0, 0, cur);
    STAGE2_(1, 0, koff, nxt);
    COMPUTE2_(0, 1, cur);
    STAGE2_(0, 1, koff, nxt);
    asm volatile("s_waitcnt vmcnt(6)" ::: "memory");
    __builtin_amdgcn_s_barrier();
    COMPUTE2_(1, 0, cur);
    STAGE2_(1, 1, koff, nxt);
    COMPUTE2_(1, 1, cur);
  }
  asm volatile("s_waitcnt vmcnt(4)" ::: "memory");
  __builtin_amdgcn_s_barrier();
  COMPUTE2_(0, 0, 1);
  COMPUTE2_(0, 1, 1);
  asm volatile("s_waitcnt vmcnt(0)" ::: "memory");
  __builtin_amdgcn_s_barrier();
  COMPUTE2_(1, 0, 1);
  COMPUTE2_(1, 1, 1);
#undef STAGE2_
#undef COMPUTE2_

  __syncthreads();

  float* st = (float*)&lds[0][0][0][0] + wid * (16 * 68);
  const int erow = lane >> 2;
  const int ecol = (lane & 3) * 16;
  const int gcb = n0 + wn * 64;
  const int qrow = (lane >> 4) * 4;
  const int qcol = lane & 15;
  f32x4 bb[4];
#pragma unroll
  for (int q = 0; q < 4; ++q) bb[q] = *(const f32x4*)&bias[gcb + ecol + q * 4];
#pragma unroll
  for (int m = 0; m < 8; ++m) {
#pragma unroll
    for (int n = 0; n < 4; ++n)
#pragma unroll
      for (int j = 0; j < 4; ++j)
        st[(qrow + j) * 68 + n * 16 + qcol] = acc[m][n][j];
    asm volatile("s_waitcnt lgkmcnt(0)" ::: "memory");
    __builtin_amdgcn_sched_barrier(0);
    const int grow = m0 + wm * 128 + m * 16 + erow;
    f32x4 v[4];
#pragma unroll
    for (int q = 0; q < 4; ++q) v[q] = *(f32x4*)&st[erow * 68 + ecol + q * 4];
#pragma unroll
    for (int q = 0; q < 4; ++q)
#pragma unroll
      for (int i = 0; i < 4; ++i) v[q][i] += bb[q][i];
    bf16x8 r0 = *(const bf16x8*)&resid[(size_t)grow * N + gcb + ecol];
    bf16x8 r1 = *(const bf16x8*)&resid[(size_t)grow * N + gcb + ecol + 8];
#pragma unroll
    for (int i = 0; i < 4; ++i) { v[0][i] += (float)r0[i]; v[1][i] += (float)r0[4 + i]; }
#pragma unroll
    for (int i = 0; i < 4; ++i) { v[2][i] += (float)r1[i]; v[3][i] += (float)r1[4 + i]; }
    float* op = Cout + (size_t)grow * N + gcb + ecol;
#pragma unroll
    for (int q = 0; q < 4; ++q) *(f32x4*)&op[q * 4] = v[q];
  }
}

// ---------------------------------------------------------------------------
// scores[b*H+h][s] = (X[b,s,:] . Wa[h,:] + ba[h]) * SCALE + mask[b][s]
// ---------------------------------------------------------------------------
template <int PER_B>
__global__ __launch_bounds__(256)
void score_kernel(const bf16_t* __restrict__ X, const bf16_t* __restrict__ WaT,
                  const float* __restrict__ ba, const float* __restrict__ mask,
                  float* __restrict__ scores) {
  const int lane = threadIdx.x & 63, wid = threadIdx.x >> 6;
  const int m0 = blockIdx.x * 64 + wid * 16;
  const int ar = lane & 15, ak = (lane >> 4) * 8;
  const int bb = m0 >> 11;
  const bf16_t* Wb = WaT + (PER_B ? (size_t)bb * H_ * D_ : 0);
  f32x4 acc = {};
  for (int k0 = 0; k0 < D_; k0 += 32) {
    bf16x8 a = *(const bf16x8*)&X[(size_t)(m0 + ar) * D_ + k0 + ak];
    bf16x8 b = *(const bf16x8*)&Wb[(size_t)ar * D_ + k0 + ak];
    acc = __builtin_amdgcn_mfma_f32_16x16x32_bf16(a, b, acc, 0, 0, 0);
  }
  const int h = lane & 15;
  const int srow = m0 + (lane >> 4) * 4;
  const int s0 = srow - bb * S_;
  const float bah = ba[h];
  f32x4 mv = *(const f32x4*)&mask[(size_t)bb * S_ + s0];
  f32x4 outv;
#pragma unroll
  for (int j = 0; j < 4; ++j)
    outv[j] = (acc[j] + bah) * SCALE + mv[j];
  *(f32x4*)&scores[((size_t)(bb * H_ + h)) * S_ + s0] = outv;
}

// ---------------------------------------------------------------------------
// row_stats: per (b,h) row of scores -> stats[bh] = (max, 1/sum_exp)
// ---------------------------------------------------------------------------
__global__ __launch_bounds__(256)
void row_stats(const float* __restrict__ scores, float* __restrict__ stats) {
  __shared__ float rA[4], rB[4];
  const int tid = threadIdx.x, lane = tid & 63, wid = tid >> 6;
  const float* srow = scores + (size_t)blockIdx.x * S_;
  f32x4 v0 = *(const f32x4*)&srow[tid * 4];
  f32x4 v1 = *(const f32x4*)&srow[1024 + tid * 4];
  float mx = fmaxf(fmaxf(fmaxf(v0[0], v0[1]), fmaxf(v0[2], v0[3])),
                   fmaxf(fmaxf(v1[0], v1[1]), fmaxf(v1[2], v1[3])));
#pragma unroll
  for (int o = 32; o; o >>= 1) mx = fmaxf(mx, __shfl_xor(mx, o));
  if (lane == 0) rA[wid] = mx;
  __syncthreads();
  mx = fmaxf(fmaxf(rA[0], rA[1]), fmaxf(rA[2], rA[3]));
  float sum = 0.f;
#pragma unroll
  for (int i = 0; i < 4; ++i) sum += __expf(v0[i] - mx) + __expf(v1[i] - mx);
#pragma unroll
  for (int o = 32; o; o >>= 1) sum += __shfl_xor(sum, o);
  if (lane == 0) rB[wid] = sum;
  __syncthreads();
  if (tid == 0) {
    float s = rB[0] + rB[1] + rB[2] + rB[3];
    stats[blockIdx.x * 2]     = mx;
    stats[blockIdx.x * 2 + 1] = 1.0f / s;
  }
}

// ---------------------------------------------------------------------------
// pool partials with on-the-fly softmax weights: w = exp(score-m)*inv
// ---------------------------------------------------------------------------
__global__ __launch_bounds__(256)
void pool_partial(const bf16_t* __restrict__ X, const float* __restrict__ scores,
                  const float* __restrict__ stats, float* __restrict__ partials) {
  __shared__ float sm[2][1024];
  const int tid = threadIdx.x;
  const int chunk = blockIdx.x, b = blockIdx.y;
  const int s0 = chunk * 32;
  const int dc = (tid & 127) * 8;
  const int sp = tid >> 7;
  const int h = dc >> 6;
  const int bh = b * H_ + h;
  const float* srow = scores + (size_t)bh * S_ + s0;
  const float m = stats[bh * 2];
  const float inv = stats[bh * 2 + 1];
  const bf16_t* Xb = X + ((size_t)b * S_ + s0) * D_ + dc;
  float acc[8] = {};
  for (int s = sp; s < 32; s += 2) {
    bf16x8 xv = *(const bf16x8*)&Xb[(size_t)s * D_];
    float wt = __expf(srow[s] - m) * inv;
#pragma unroll
    for (int j = 0; j < 8; ++j) acc[j] += wt * (float)xv[j];
  }
#pragma unroll
  for (int j = 0; j < 8; ++j) sm[sp][dc + j] = acc[j];
  __syncthreads();
  const int d0 = tid * 4;
  f32x4 r;
#pragma unroll
  for (int j = 0; j < 4; ++j) r[j] = sm[0][d0 + j] + sm[1][d0 + j];
  *(f32x4*)&partials[((size_t)chunk * B_ + b) * D_ + d0] = r;
}

// MODE 0: pq[idx] = sum; ALSO write wka_s[b][h][d] = bf16(pq * Wka[h][d])
// MODE 1: pk[idx] = sum * pq[idx]
template <int MODE>
__global__ __launch_bounds__(256)
void pool_reduce(const float* __restrict__ partials, const float* __restrict__ pq,
                 const bf16_t* __restrict__ WkaT, float* __restrict__ pooled,
                 bf16_t* __restrict__ wka_s) {
  const int idx = blockIdx.x * 256 + threadIdx.x;
  float s = 0.f;
#pragma unroll 8
  for (int c = 0; c < 64; ++c) s += partials[(size_t)c * (B_ * D_) + idx];
  if (MODE == 1) s *= pq[idx];
  pooled[idx] = s;
  if (MODE == 0) {
    const int b = idx >> 10, d = idx & 1023;
#pragma unroll
    for (int h = 0; h < H_; ++h)
      wka_s[((size_t)b * H_ + h) * D_ + d] = (bf16_t)(s * (float)WkaT[h * D_ + d]);
  }
}

// ---------------------------------------------------------------------------
extern "C" void kernel_launch(void* const* d_in, const int* in_sizes, int n_in,
                              void* d_out, int out_size, void* d_ws, size_t ws_size,
                              hipStream_t stream) {
  const float* hs   = (const float*)d_in[0];
  const float* mask = (const float*)d_in[1];
  const float* Wq   = (const float*)d_in[2];
  const float* bq   = (const float*)d_in[3];
  const float* Wqa  = (const float*)d_in[4];
  const float* bqa  = (const float*)d_in[5];
  const float* Wk   = (const float*)d_in[6];
  const float* bk   = (const float*)d_in[7];
  const float* Wka  = (const float*)d_in[8];
  const float* bka  = (const float*)d_in[9];
  const float* Wt   = (const float*)d_in[10];
  const float* bt   = (const float*)d_in[11];

  char* ws = (char*)d_ws;
  float*  pq    = (float*)(ws + (64u << 10));
  float*  pk    = (float*)(ws + (128u << 10));
  float*  stats = (float*)(ws + (160u << 10));
  bf16_t* wka_s = (bf16_t*)(ws + (256u << 10));
  bf16_t* WqaT  = (bf16_t*)(ws + (1u << 20));
  bf16_t* WkaT  = (bf16_t*)(ws + (1u << 20) + 32768);
  bf16_t* WqT   = (bf16_t*)(ws + (2u << 20));
  bf16_t* WkT   = (bf16_t*)(ws + (4u << 20));
  bf16_t* WtT   = (bf16_t*)(ws + (6u << 20));
  bf16_t* hsb   = (bf16_t*)(ws + (8u << 20));
  bf16_t* mq    = (bf16_t*)(ws + (8u << 20) + ((size_t)64 << 20));
  bf16_t* mk    = (bf16_t*)(ws + (8u << 20) + ((size_t)128 << 20));
  float* scores = (float*)(ws + (8u << 20) + ((size_t)192 << 20));
  float* parts  = (float*)(ws + (8u << 20) + ((size_t)196 << 20));
  bf16_t* wt_s  = (bf16_t*)(ws + (8u << 20) + ((size_t)208 << 20));

  prep_all<<<dim3(16, 16, 20), 256, 0, stream>>>(Wq, Wk, Wt, Wqa, Wka, hs,
                                                 WqT, WkT, WtT, WqaT, WkaT, hsb);

  gemm_qk<<<1024, 512, 0, stream>>>(hsb, WqT, WkT, bq, bk, mq, mk);

  score_kernel<0><<<512, 256, 0, stream>>>(mq, WqaT, bqa, mask, scores);
  row_stats<<<256, 256, 0, stream>>>(scores, stats);
  pool_partial<<<dim3(64, 16), 256, 0, stream>>>(mq, scores, stats, parts);
  pool_reduce<0><<<64, 256, 0, stream>>>(parts, nullptr, WkaT, pq, wka_s);

  score_kernel<1><<<512, 256, 0, stream>>>(mk, wka_s, bka, mask, scores);
  row_stats<<<256, 256, 0, stream>>>(scores, stats);
  pool_partial<<<dim3(64, 16), 256, 0, stream>>>(mk, scores, stats, parts);
  pool_reduce<1><<<64, 256, 0, stream>>>(parts, pq, nullptr, pk, nullptr);

  wt_scale<<<8192, 256, 0, stream>>>(WtT, pk, wt_s);
  gemm_out8<<<512, 512, 0, stream>>>(mq, wt_s, bt, (float*)d_out, mq);
}

// Round 19
// 358.314 us; speedup vs baseline: 1.0062x; 1.0062x over previous
//
#include <hip/hip_runtime.h>
#include <hip/hip_bf16.h>
#include <stdint.h>

#define D_ 1024
#define H_ 16
#define DH_ 64
#define S_ 2048
#define B_ 16
static constexpr float SCALE = 0.125f;  // 1/sqrt(64)

typedef __bf16 bf16_t;
typedef __bf16 bf16x8 __attribute__((ext_vector_type(8)));
typedef __bf16 bf16x4 __attribute__((ext_vector_type(4)));
typedef float  f32x4  __attribute__((ext_vector_type(4)));

__device__ __forceinline__ void llds16(const void* g, void* l) {
  __builtin_amdgcn_global_load_lds(
      (const __attribute__((address_space(1))) void*)g,
      (__attribute__((address_space(3))) void*)l, 16, 0, 0);
}

// ---------------------------------------------------------------------------
// prep_all: one launch for all input preprocessing.
// ---------------------------------------------------------------------------
__global__ __launch_bounds__(256)
void prep_all(const float* __restrict__ Wq, const float* __restrict__ Wk,
              const float* __restrict__ Wt, const float* __restrict__ Wqa,
              const float* __restrict__ Wka, const float* __restrict__ hs,
              bf16_t* __restrict__ WqT, bf16_t* __restrict__ WkT,
              bf16_t* __restrict__ WtT, bf16_t* __restrict__ WqaT,
              bf16_t* __restrict__ WkaT, bf16_t* __restrict__ hsb) {
  __shared__ bf16_t t[64][65];
  const int z = blockIdx.z;
  const int tid = threadIdx.x;
  if (z < 3) {
    const float* src = (z == 0) ? Wq : (z == 1) ? Wk : Wt;
    bf16_t* dst      = (z == 0) ? WqT : (z == 1) ? WkT : WtT;
    const int n0 = blockIdx.x * 64, k0 = blockIdx.y * 64;
    const int r = tid >> 4, c4 = (tid & 15) * 4;
#pragma unroll
    for (int p = 0; p < 4; ++p) {
      int row = p * 16 + r;
      f32x4 f = *(const f32x4*)&src[(size_t)(k0 + row) * 1024 + n0 + c4];
#pragma unroll
      for (int i = 0; i < 4; ++i) t[row][c4 + i] = (bf16_t)f[i];
    }
    __syncthreads();
#pragma unroll
    for (int p = 0; p < 4; ++p) {
      int row = p * 16 + r;
      bf16x4 v;
#pragma unroll
      for (int i = 0; i < 4; ++i) v[i] = t[c4 + i][row];
      *(bf16x4*)&dst[(size_t)(n0 + row) * 1024 + k0 + c4] = v;
    }
  } else if (z == 3) {
    int g = (blockIdx.y * 16 + blockIdx.x) * 256 + tid;
    if (g < 2048) {
      const float* src = (g < 1024) ? Wqa : Wka;
      bf16_t* dst      = (g < 1024) ? WqaT : WkaT;
      int k = g & 1023;
#pragma unroll
      for (int h = 0; h < H_; ++h) dst[h * 1024 + k] = (bf16_t)src[k * H_ + h];
    }
  } else {
    const int slice = z - 4;
    const int fb = blockIdx.y * 16 + blockIdx.x;
    const size_t tbase = ((size_t)slice * 256 + fb) * 256 + tid;
#pragma unroll
    for (int i = 0; i < 4; ++i) {
      size_t e = (tbase + (size_t)i * 1048576) * 8;
      f32x4 a = *(const f32x4*)&hs[e];
      f32x4 b = *(const f32x4*)&hs[e + 4];
      bf16x8 o;
#pragma unroll
      for (int j = 0; j < 4; ++j) { o[j] = (bf16_t)a[j]; o[4 + j] = (bf16_t)b[j]; }
      *(bf16x8*)&hsb[e] = o;
    }
  }
}

// ---------------------------------------------------------------------------
// Dual-N 256x256 8-phase GEMM (r16 best-measured form: 2 barriers/tile,
// counted vmcnt(6), slot-rotation swizzle (r>>1)&3 => 0 conflicts,
// setprio MFMA clusters, staged epilogue). MfmaUtil 41%, 146us.
// r18's per-phase barriers regressed (155us) — reverted.
// ---------------------------------------------------------------------------
__global__ __launch_bounds__(512, 1)
void gemm_qk(const bf16_t* __restrict__ A, const bf16_t* __restrict__ WqT,
             const bf16_t* __restrict__ WkT, const float* __restrict__ bq,
             const float* __restrict__ bk, bf16_t* __restrict__ mq,
             bf16_t* __restrict__ mk) {
  constexpr int K = 1024, N = 1024;
  __shared__ __align__(16) bf16_t lds[2][2][2][256 * 32];
  const int tid = threadIdx.x;
  const int lane = tid & 63, wid = tid >> 6;
  const int wm = wid >> 2, wn = wid & 3;

  const int wgid = (blockIdx.x & 7) * 128 + (blockIdx.x >> 3);
  const int m0 = (wgid >> 3) * 256;
  const int nsel = wgid & 7;
  const int n0 = (nsel & 3) * 256;
  const bf16_t* BT = (nsel < 4) ? WqT : WkT;
  const float* bias = (nsel < 4) ? bq : bk;
  bf16_t* Cout = (nsel < 4) ? mq : mk;

  int srow[2], scol[2];
#pragma unroll
  for (int ld = 0; ld < 2; ++ld) {
    int c = ld * 512 + tid;
    srow[ld] = c >> 2;
    scol[ld] = (((c & 3) - ((srow[ld] >> 1) & 3)) & 3) * 8;
  }

  const int ar = lane & 15;
  const int kc = lane >> 4;

  f32x4 acc[8][4] = {};

#define STAGE_(MAT, KH, KOFF, NXT)                                             \
  {                                                                            \
    const bf16_t* srcb = (MAT == 0) ? A : BT;                                  \
    const int rb = (MAT == 0) ? m0 : n0;                                       \
    _Pragma("unroll")                                                          \
    for (int ld = 0; ld < 2; ++ld) {                                           \
      llds16(srcb + (size_t)(rb + srow[ld]) * K + (KOFF) + (KH) * 32 + scol[ld], \
             &lds[NXT][MAT][KH][(ld * 512 + tid) * 8]);                        \
    }                                                                          \
  }

#define COMPUTE_(KH, MH, CUR)                                                  \
  {                                                                            \
    bf16x8 af[4], bg[4];                                                       \
    _Pragma("unroll")                                                          \
    for (int mm = 0; mm < 4; ++mm) {                                           \
      int r = wm * 128 + ((MH) * 4 + mm) * 16 + ar;                            \
      int slot = (kc + ((r >> 1) & 3)) & 3;                                    \
      af[mm] = *(const bf16x8*)&lds[CUR][0][KH][r * 32 + slot * 8];            \
    }                                                                          \
    _Pragma("unroll")                                                          \
    for (int nn = 0; nn < 4; ++nn) {                                           \
      int r = wn * 64 + nn * 16 + ar;                                          \
      int slot = (kc + ((r >> 1) & 3)) & 3;                                    \
      bg[nn] = *(const bf16x8*)&lds[CUR][1][KH][r * 32 + slot * 8];            \
    }                                                                          \
    __builtin_amdgcn_s_setprio(1);                                             \
    _Pragma("unroll")                                                          \
    for (int mm = 0; mm < 4; ++mm)                                             \
      _Pragma("unroll")                                                        \
      for (int nn = 0; nn < 4; ++nn)                                           \
        acc[(MH) * 4 + mm][nn] = __builtin_amdgcn_mfma_f32_16x16x32_bf16(      \
            af[mm], bg[nn], acc[(MH) * 4 + mm][nn], 0, 0, 0);                  \
    __builtin_amdgcn_s_setprio(0);                                             \
  }

  STAGE_(0, 0, 0, 0); STAGE_(1, 0, 0, 0); STAGE_(0, 1, 0, 0); STAGE_(1, 1, 0, 0);

#pragma unroll 1
  for (int t = 0; t < 15; ++t) {
    const int cur = t & 1, nxt = cur ^ 1;
    const int koff = (t + 1) * 64;
    STAGE_(0, 0, koff, nxt);
    asm volatile("s_waitcnt vmcnt(6)" ::: "memory");
    __builtin_amdgcn_s_barrier();
    COMPUTE_(0, 0, cur);
    STAGE_(1, 0, koff, nxt);
    COMPUTE_(0, 1, cur);
    STAGE_(0, 1, koff, nxt);
    asm volatile("s_waitcnt vmcnt(6)" ::: "memory");
    __builtin_amdgcn_s_barrier();
    COMPUTE_(1, 0, cur);
    STAGE_(1, 1, koff, nxt);
    COMPUTE_(1, 1, cur);
  }
  asm volatile("s_waitcnt vmcnt(4)" ::: "memory");
  __builtin_amdgcn_s_barrier();
  COMPUTE_(0, 0, 1);
  COMPUTE_(0, 1, 1);
  asm volatile("s_waitcnt vmcnt(0)" ::: "memory");
  __builtin_amdgcn_s_barrier();
  COMPUTE_(1, 0, 1);
  COMPUTE_(1, 1, 1);
#undef STAGE_
#undef COMPUTE_

  __syncthreads();

  float* st = (float*)&lds[0][0][0][0] + wid * (16 * 68);
  const int erow = lane >> 2;
  const int ecol = (lane & 3) * 16;
  const int gcb = n0 + wn * 64;
  const int qrow = (lane >> 4) * 4;
  const int qcol = lane & 15;
  f32x4 bb[4];
#pragma unroll
  for (int q = 0; q < 4; ++q) bb[q] = *(const f32x4*)&bias[gcb + ecol + q * 4];
#pragma unroll
  for (int m = 0; m < 8; ++m) {
#pragma unroll
    for (int n = 0; n < 4; ++n)
#pragma unroll
      for (int j = 0; j < 4; ++j)
        st[(qrow + j) * 68 + n * 16 + qcol] = acc[m][n][j];
    asm volatile("s_waitcnt lgkmcnt(0)" ::: "memory");
    __builtin_amdgcn_sched_barrier(0);
    const int grow = m0 + wm * 128 + m * 16 + erow;
    f32x4 v[4];
#pragma unroll
    for (int q = 0; q < 4; ++q) v[q] = *(f32x4*)&st[erow * 68 + ecol + q * 4];
#pragma unroll
    for (int q = 0; q < 4; ++q)
#pragma unroll
      for (int i = 0; i < 4; ++i) v[q][i] += bb[q][i];
    bf16x8 o0, o1;
#pragma unroll
    for (int i = 0; i < 4; ++i) { o0[i] = (bf16_t)v[0][i]; o0[4 + i] = (bf16_t)v[1][i]; }
#pragma unroll
    for (int i = 0; i < 4; ++i) { o1[i] = (bf16_t)v[2][i]; o1[4 + i] = (bf16_t)v[3][i]; }
    bf16_t* op = Cout + (size_t)grow * N + gcb + ecol;
    *(bf16x8*)&op[0] = o0;
    *(bf16x8*)&op[8] = o1;
  }
}

// ---------------------------------------------------------------------------
// wt_s[b][n][k] = bf16(pk[b,k] * WtT[n,k])
// ---------------------------------------------------------------------------
__global__ __launch_bounds__(256)
void wt_scale(const bf16_t* __restrict__ WtT, const float* __restrict__ pk,
              bf16_t* __restrict__ wt_s) {
  size_t e = ((size_t)blockIdx.x * 256 + threadIdx.x) * 8;
  const int b = (int)(e >> 20);
  const int nk = (int)(e & 1048575);
  const int k = nk & 1023;
  bf16x8 w = *(const bf16x8*)&WtT[nk];
  const float* pp = &pk[b * D_ + k];
  f32x4 p0 = *(const f32x4*)pp;
  f32x4 p1 = *(const f32x4*)(pp + 4);
  bf16x8 o;
#pragma unroll
  for (int i = 0; i < 4; ++i) {
    o[i]     = (bf16_t)((float)w[i] * p0[i]);
    o[4 + i] = (bf16_t)((float)w[4 + i] * p1[i]);
  }
  *(bf16x8*)&wt_s[e] = o;
}

// ---------------------------------------------------------------------------
// Final GEMM, 8-phase: out = mq @ wt_s[b] + bt + resid(mq) -> f32
// ---------------------------------------------------------------------------
__global__ __launch_bounds__(512, 1)
void gemm_out8(const bf16_t* __restrict__ A, const bf16_t* __restrict__ WtS,
               const float* __restrict__ bias, float* __restrict__ Cout,
               const bf16_t* __restrict__ resid) {
  constexpr int K = 1024, N = 1024;
  __shared__ __align__(16) bf16_t lds[2][2][2][256 * 32];
  const int tid = threadIdx.x;
  const int lane = tid & 63, wid = tid >> 6;
  const int wm = wid >> 2, wn = wid & 3;

  const int wgid = (blockIdx.x & 7) * 64 + (blockIdx.x >> 3);
  const int m0 = (wgid >> 2) * 256;
  const int n0 = (wgid & 3) * 256;
  const bf16_t* BT = WtS + ((size_t)(m0 >> 11) << 20);

  int srow[2], scol[2];
#pragma unroll
  for (int ld = 0; ld < 2; ++ld) {
    int c = ld * 512 + tid;
    srow[ld] = c >> 2;
    scol[ld] = (((c & 3) - ((srow[ld] >> 1) & 3)) & 3) * 8;
  }

  const int ar = lane & 15;
  const int kc = lane >> 4;

  f32x4 acc[8][4] = {};

#define STAGE2_(MAT, KH, KOFF, NXT)                                            \
  {                                                                            \
    const bf16_t* srcb = (MAT == 0) ? A : BT;                                  \
    const int rb = (MAT == 0) ? m0 : n0;                                       \
    _Pragma("unroll")                                                          \
    for (int ld = 0; ld < 2; ++ld) {                                           \
      llds16(srcb + (size_t)(rb + srow[ld]) * K + (KOFF) + (KH) * 32 + scol[ld], \
             &lds[NXT][MAT][KH][(ld * 512 + tid) * 8]);                        \
    }                                                                          \
  }

#define COMPUTE2_(KH, MH, CUR)                                                 \
  {                                                                            \
    bf16x8 af[4], bg[4];                                                       \
    _Pragma("unroll")                                                          \
    for (int mm = 0; mm < 4; ++mm) {                                           \
      int r = wm * 128 + ((MH) * 4 + mm) * 16 + ar;                            \
      int slot = (kc + ((r >> 1) & 3)) & 3;                                    \
      af[mm] = *(const bf16x8*)&lds[CUR][0][KH][r * 32 + slot * 8];            \
    }                                                                          \
    _Pragma("unroll")                                                          \
    for (int nn = 0; nn < 4; ++nn) {                                           \
      int r = wn * 64 + nn * 16 + ar;                                          \
      int slot = (kc + ((r >> 1) & 3)) & 3;                                    \
      bg[nn] = *(const bf16x8*)&lds[CUR][1][KH][r * 32 + slot * 8];            \
    }                                                                          \
    __builtin_amdgcn_s_setprio(1);                                             \
    _Pragma("unroll")                                                          \
    for (int mm = 0; mm < 4; ++mm)                                             \
      _Pragma("unroll")                                                        \
      for (int nn = 0; nn < 4; ++nn)                                           \
        acc[(MH) * 4 + mm][nn] = __builtin_amdgcn_mfma_f32_16x16x32_bf16(      \
            af[mm], bg[nn], acc[(MH) * 4 + mm][nn], 0, 0, 0);                  \
    __builtin_amdgcn_s_setprio(0);                                             \
  }

  STAGE2_(0, 0, 0, 0); STAGE2_(1, 0, 0, 0); STAGE2_(0, 1, 0, 0); STAGE2_(1, 1, 0, 0);

#pragma unroll 1
  for (int t = 0; t < 15; ++t) {
    const int cur = t & 1, nxt = cur ^ 1;
    const int koff = (t + 1) * 64;
    STAGE2_(0, 0, koff, nxt);
    asm volatile("s_waitcnt vmcnt(6)" ::: "memory");
    __builtin_amdgcn_s_barrier();
    COMPUTE2_(0, 0, cur);
    STAGE2_(1, 0, koff, nxt);
    COMPUTE2_(0, 1, cur);
    STAGE2_(0, 1, koff, nxt);
    asm volatile("s_waitcnt vmcnt(6)" ::: "memory");
    __builtin_amdgcn_s_barrier();
    COMPUTE2_(1, 0, cur);
    STAGE2_(1, 1, koff, nxt);
    COMPUTE2_(1, 1, cur);
  }
  asm volatile("s_waitcnt vmcnt(4)" ::: "memory");
  __builtin_amdgcn_s_barrier();
  COMPUTE2_(0, 0, 1);
  COMPUTE2_(0, 1, 1);
  asm volatile("s_waitcnt vmcnt(0)" ::: "memory");
  __builtin_amdgcn_s_barrier();
  COMPUTE2_(1, 0, 1);
  COMPUTE2_(1, 1, 1);
#undef STAGE2_
#undef COMPUTE2_

  __syncthreads();

  float* st = (float*)&lds[0][0][0][0] + wid * (16 * 68);
  const int erow = lane >> 2;
  const int ecol = (lane & 3) * 16;
  const int gcb = n0 + wn * 64;
  const int qrow = (lane >> 4) * 4;
  const int qcol = lane & 15;
  f32x4 bb[4];
#pragma unroll
  for (int q = 0; q < 4; ++q) bb[q] = *(const f32x4*)&bias[gcb + ecol + q * 4];
#pragma unroll
  for (int m = 0; m < 8; ++m) {
#pragma unroll
    for (int n = 0; n < 4; ++n)
#pragma unroll
      for (int j = 0; j < 4; ++j)
        st[(qrow + j) * 68 + n * 16 + qcol] = acc[m][n][j];
    asm volatile("s_waitcnt lgkmcnt(0)" ::: "memory");
    __builtin_amdgcn_sched_barrier(0);
    const int grow = m0 + wm * 128 + m * 16 + erow;
    f32x4 v[4];
#pragma unroll
    for (int q = 0; q < 4; ++q) v[q] = *(f32x4*)&st[erow * 68 + ecol + q * 4];
#pragma unroll
    for (int q = 0; q < 4; ++q)
#pragma unroll
      for (int i = 0; i < 4; ++i) v[q][i] += bb[q][i];
    bf16x8 r0 = *(const bf16x8*)&resid[(size_t)grow * N + gcb + ecol];
    bf16x8 r1 = *(const bf16x8*)&resid[(size_t)grow * N + gcb + ecol + 8];
#pragma unroll
    for (int i = 0; i < 4; ++i) { v[0][i] += (float)r0[i]; v[1][i] += (float)r0[4 + i]; }
#pragma unroll
    for (int i = 0; i < 4; ++i) { v[2][i] += (float)r1[i]; v[3][i] += (float)r1[4 + i]; }
    float* op = Cout + (size_t)grow * N + gcb + ecol;
#pragma unroll
    for (int q = 0; q < 4; ++q) *(f32x4*)&op[q * 4] = v[q];
  }
}

// ---------------------------------------------------------------------------
// scores[b*H+h][s] = (X[b,s,:] . Wa[h,:] + ba[h]) * SCALE + mask[b][s]
// ---------------------------------------------------------------------------
template <int PER_B>
__global__ __launch_bounds__(256)
void score_kernel(const bf16_t* __restrict__ X, const bf16_t* __restrict__ WaT,
                  const float* __restrict__ ba, const float* __restrict__ mask,
                  float* __restrict__ scores) {
  const int lane = threadIdx.x & 63, wid = threadIdx.x >> 6;
  const int m0 = blockIdx.x * 64 + wid * 16;
  const int ar = lane & 15, ak = (lane >> 4) * 8;
  const int bb = m0 >> 11;
  const bf16_t* Wb = WaT + (PER_B ? (size_t)bb * H_ * D_ : 0);
  f32x4 acc = {};
  for (int k0 = 0; k0 < D_; k0 += 32) {
    bf16x8 a = *(const bf16x8*)&X[(size_t)(m0 + ar) * D_ + k0 + ak];
    bf16x8 b = *(const bf16x8*)&Wb[(size_t)ar * D_ + k0 + ak];
    acc = __builtin_amdgcn_mfma_f32_16x16x32_bf16(a, b, acc, 0, 0, 0);
  }
  const int h = lane & 15;
  const int srow = m0 + (lane >> 4) * 4;
  const int s0 = srow - bb * S_;
  const float bah = ba[h];
  f32x4 mv = *(const f32x4*)&mask[(size_t)bb * S_ + s0];
  f32x4 outv;
#pragma unroll
  for (int j = 0; j < 4; ++j)
    outv[j] = (acc[j] + bah) * SCALE + mv[j];
  *(f32x4*)&scores[((size_t)(bb * H_ + h)) * S_ + s0] = outv;
}

// ---------------------------------------------------------------------------
// row_stats: per (b,h) row of scores -> stats[bh] = (max, 1/sum_exp)
// ---------------------------------------------------------------------------
__global__ __launch_bounds__(256)
void row_stats(const float* __restrict__ scores, float* __restrict__ stats) {
  __shared__ float rA[4], rB[4];
  const int tid = threadIdx.x, lane = tid & 63, wid = tid >> 6;
  const float* srow = scores + (size_t)blockIdx.x * S_;
  f32x4 v0 = *(const f32x4*)&srow[tid * 4];
  f32x4 v1 = *(const f32x4*)&srow[1024 + tid * 4];
  float mx = fmaxf(fmaxf(fmaxf(v0[0], v0[1]), fmaxf(v0[2], v0[3])),
                   fmaxf(fmaxf(v1[0], v1[1]), fmaxf(v1[2], v1[3])));
#pragma unroll
  for (int o = 32; o; o >>= 1) mx = fmaxf(mx, __shfl_xor(mx, o));
  if (lane == 0) rA[wid] = mx;
  __syncthreads();
  mx = fmaxf(fmaxf(rA[0], rA[1]), fmaxf(rA[2], rA[3]));
  float sum = 0.f;
#pragma unroll
  for (int i = 0; i < 4; ++i) sum += __expf(v0[i] - mx) + __expf(v1[i] - mx);
#pragma unroll
  for (int o = 32; o; o >>= 1) sum += __shfl_xor(sum, o);
  if (lane == 0) rB[wid] = sum;
  __syncthreads();
  if (tid == 0) {
    float s = rB[0] + rB[1] + rB[2] + rB[3];
    stats[blockIdx.x * 2]     = mx;
    stats[blockIdx.x * 2 + 1] = 1.0f / s;
  }
}

// ---------------------------------------------------------------------------
// pool partials with on-the-fly softmax weights: w = exp(score-m)*inv
// ---------------------------------------------------------------------------
__global__ __launch_bounds__(256)
void pool_partial(const bf16_t* __restrict__ X, const float* __restrict__ scores,
                  const float* __restrict__ stats, float* __restrict__ partials) {
  __shared__ float sm[2][1024];
  const int tid = threadIdx.x;
  const int chunk = blockIdx.x, b = blockIdx.y;
  const int s0 = chunk * 32;
  const int dc = (tid & 127) * 8;
  const int sp = tid >> 7;
  const int h = dc >> 6;
  const int bh = b * H_ + h;
  const float* srow = scores + (size_t)bh * S_ + s0;
  const float m = stats[bh * 2];
  const float inv = stats[bh * 2 + 1];
  const bf16_t* Xb = X + ((size_t)b * S_ + s0) * D_ + dc;
  float acc[8] = {};
  for (int s = sp; s < 32; s += 2) {
    bf16x8 xv = *(const bf16x8*)&Xb[(size_t)s * D_];
    float wt = __expf(srow[s] - m) * inv;
#pragma unroll
    for (int j = 0; j < 8; ++j) acc[j] += wt * (float)xv[j];
  }
#pragma unroll
  for (int j = 0; j < 8; ++j) sm[sp][dc + j] = acc[j];
  __syncthreads();
  const int d0 = tid * 4;
  f32x4 r;
#pragma unroll
  for (int j = 0; j < 4; ++j) r[j] = sm[0][d0 + j] + sm[1][d0 + j];
  *(f32x4*)&partials[((size_t)chunk * B_ + b) * D_ + d0] = r;
}

// MODE 0: pq[idx] = sum; ALSO write wka_s[b][h][d] = bf16(pq * Wka[h][d])
// MODE 1: pk[idx] = sum * pq[idx]
template <int MODE>
__global__ __launch_bounds__(256)
void pool_reduce(const float* __restrict__ partials, const float* __restrict__ pq,
                 const bf16_t* __restrict__ WkaT, float* __restrict__ pooled,
                 bf16_t* __restrict__ wka_s) {
  const int idx = blockIdx.x * 256 + threadIdx.x;
  float s = 0.f;
#pragma unroll 8
  for (int c = 0; c < 64; ++c) s += partials[(size_t)c * (B_ * D_) + idx];
  if (MODE == 1) s *= pq[idx];
  pooled[idx] = s;
  if (MODE == 0) {
    const int b = idx >> 10, d = idx & 1023;
#pragma unroll
    for (int h = 0; h < H_; ++h)
      wka_s[((size_t)b * H_ + h) * D_ + d] = (bf16_t)(s * (float)WkaT[h * D_ + d]);
  }
}

// ---------------------------------------------------------------------------
extern "C" void kernel_launch(void* const* d_in, const int* in_sizes, int n_in,
                              void* d_out, int out_size, void* d_ws, size_t ws_size,
                              hipStream_t stream) {
  const float* hs   = (const float*)d_in[0];
  const float* mask = (const float*)d_in[1];
  const float* Wq   = (const float*)d_in[2];
  const float* bq   = (const float*)d_in[3];
  const float* Wqa  = (const float*)d_in[4];
  const float* bqa  = (const float*)d_in[5];
  const float* Wk   = (const float*)d_in[6];
  const float* bk   = (const float*)d_in[7];
  const float* Wka  = (const float*)d_in[8];
  const float* bka  = (const float*)d_in[9];
  const float* Wt   = (const float*)d_in[10];
  const float* bt   = (const float*)d_in[11];

  char* ws = (char*)d_ws;
  float*  pq    = (float*)(ws + (64u << 10));
  float*  pk    = (float*)(ws + (128u << 10));
  float*  stats = (float*)(ws + (160u << 10));
  bf16_t* wka_s = (bf16_t*)(ws + (256u << 10));
  bf16_t* WqaT  = (bf16_t*)(ws + (1u << 20));
  bf16_t* WkaT  = (bf16_t*)(ws + (1u << 20) + 32768);
  bf16_t* WqT   = (bf16_t*)(ws + (2u << 20));
  bf16_t* WkT   = (bf16_t*)(ws + (4u << 20));
  bf16_t* WtT   = (bf16_t*)(ws + (6u << 20));
  bf16_t* hsb   = (bf16_t*)(ws + (8u << 20));
  bf16_t* mq    = (bf16_t*)(ws + (8u << 20) + ((size_t)64 << 20));
  bf16_t* mk    = (bf16_t*)(ws + (8u << 20) + ((size_t)128 << 20));
  float* scores = (float*)(ws + (8u << 20) + ((size_t)192 << 20));
  float* parts  = (float*)(ws + (8u << 20) + ((size_t)196 << 20));
  bf16_t* wt_s  = (bf16_t*)(ws + (8u << 20) + ((size_t)208 << 20));

  prep_all<<<dim3(16, 16, 20), 256, 0, stream>>>(Wq, Wk, Wt, Wqa, Wka, hs,
                                                 WqT, WkT, WtT, WqaT, WkaT, hsb);

  gemm_qk<<<1024, 512, 0, stream>>>(hsb, WqT, WkT, bq, bk, mq, mk);

  score_kernel<0><<<512, 256, 0, stream>>>(mq, WqaT, bqa, mask, scores);
  row_stats<<<256, 256, 0, stream>>>(scores, stats);
  pool_partial<<<dim3(64, 16), 256, 0, stream>>>(mq, scores, stats, parts);
  pool_reduce<0><<<64, 256, 0, stream>>>(parts, nullptr, WkaT, pq, wka_s);

  score_kernel<1><<<512, 256, 0, stream>>>(mk, wka_s, bka, mask, scores);
  row_stats<<<256, 256, 0, stream>>>(scores, stats);
  pool_partial<<<dim3(64, 16), 256, 0, stream>>>(mk, scores, stats, parts);
  pool_reduce<1><<<64, 256, 0, stream>>>(parts, pq, nullptr, pk, nullptr);

  wt_scale<<<8192, 256, 0, stream>>>(WtT, pk, wt_s);
  gemm_out8<<<512, 512, 0, stream>>>(mq, wt_s, bt, (float*)d_out, mq);
}